// Round 1
// baseline (538.263 us; speedup 1.0000x reference)
//
#include <hip/hip_runtime.h>

// ---------------------------------------------------------------------------
// Fused QKV-proj + MHA (B=4,N=1024,D=1024,H=16,DH=64) with deterministic
// inverted dropout. All matmul paths use f16 MFMA; softmax-critical paths
// (proj for q/k, QK^T) use hi/lo f16 split 3-term products (~fp32 accuracy).
// ---------------------------------------------------------------------------

typedef _Float16 f16;
typedef _Float16 f16x4 __attribute__((ext_vector_type(4)));
typedef _Float16 f16x8 __attribute__((ext_vector_type(8)));
typedef float    f32x4 __attribute__((ext_vector_type(4)));

#define MFMA16(a, b, c) __builtin_amdgcn_mfma_f32_16x16x32_f16((a), (b), (c), 0, 0, 0)

__device__ __forceinline__ void gll16(const f16* g, f16* l) {
  // async global->LDS, 16B per lane; dest must be linear in lane order
  __builtin_amdgcn_global_load_lds(
      (const __attribute__((address_space(1))) unsigned int*)g,
      (__attribute__((address_space(3))) unsigned int*)l, 16, 0, 0);
}

// swizzled fragment read from a [64 rows][64 f16] tile (128B rows, XOR-8 swz)
__device__ __forceinline__ f16x8 ldsfrag(const f16* tile, int row, int chunk) {
  return *(const f16x8*)&tile[row * 64 + ((chunk ^ (row & 7)) << 3)];
}

// --------------------------- convert fp32 -> hi/lo f16 ----------------------
__global__ __launch_bounds__(256) void cvt_split(const float4* __restrict__ s,
                                                 f16x4* __restrict__ hi,
                                                 f16x4* __restrict__ lo, int n4) {
  int i = blockIdx.x * 256 + threadIdx.x;
  if (i >= n4) return;
  float4 v = s[i];
  f16x4 h, l;
  h[0] = (f16)v.x; l[0] = (f16)(v.x - (float)h[0]);
  h[1] = (f16)v.y; l[1] = (f16)(v.y - (float)h[1]);
  h[2] = (f16)v.z; l[2] = (f16)(v.z - (float)h[2]);
  h[3] = (f16)v.w; l[3] = (f16)(v.w - (float)h[3]);
  hi[i] = h; lo[i] = l;
}

// --------------------------- QKV projection GEMM ----------------------------
// C[4096][3072] = query @ W^T + b; q/k columns via 3-term hi/lo, v via 1-term.
// 128x128 tile, BK=32, 4 waves, 16x16x32 MFMA (m97 structure).
__global__ __launch_bounds__(256) void proj_gemm(
    const f16* __restrict__ qh, const f16* __restrict__ ql,
    const f16* __restrict__ wh, const f16* __restrict__ wl,
    const float* __restrict__ bias,
    f16* __restrict__ Qh, f16* __restrict__ Ql,
    f16* __restrict__ Kh, f16* __restrict__ Kl,
    f16* __restrict__ Vh) {
  __shared__ f16 As[128 * 32];  // [row][k] rows of 64B, linear
  __shared__ f16 Bs[128 * 32];
  const int tid = threadIdx.x;
  const int m0 = blockIdx.y * 128, n0 = blockIdx.x * 128;
  const int wid = tid >> 6, lane = tid & 63;
  const int wm = (wid >> 1) * 64, wn = (wid & 1) * 64;
  const int r16 = lane & 15, g = lane >> 4;

  f32x4 zero4 = {0.f, 0.f, 0.f, 0.f};
  f32x4 acc[4][4];
#pragma unroll
  for (int i = 0; i < 4; ++i)
#pragma unroll
    for (int j = 0; j < 4; ++j) acc[i][j] = zero4;

  const f16* At[3] = {qh, ql, qh};
  const f16* Bt[3] = {wh, wh, wl};
  const int nsteps = (n0 < 2048) ? 96 : 32;  // v-cols need only the hi*hi term

  for (int s = 0; s < nsteps; ++s) {
    const int term = s >> 5, kk = (s & 31) << 5;
    const f16* Ab = At[term] + (size_t)m0 * 1024 + kk;
    const f16* Bb = Bt[term] + (size_t)n0 * 1024 + kk;
#pragma unroll
    for (int it = 0; it < 2; ++it) {
      int c = tid + it * 256;           // chunk 0..511
      int row = c >> 2, cc = c & 3;     // 4x16B chunks per 64B row
      gll16(Ab + row * 1024 + cc * 8, &As[c * 8]);
      gll16(Bb + row * 1024 + cc * 8, &Bs[c * 8]);
    }
    __syncthreads();  // drains vmcnt before barrier (compiler-guaranteed)
    f16x8 a[4], b[4];
#pragma unroll
    for (int i = 0; i < 4; ++i) {
      a[i] = *(const f16x8*)&As[(wm + i * 16 + r16) * 32 + g * 8];
      b[i] = *(const f16x8*)&Bs[(wn + i * 16 + r16) * 32 + g * 8];
    }
#pragma unroll
    for (int i = 0; i < 4; ++i)
#pragma unroll
      for (int j = 0; j < 4; ++j) acc[i][j] = MFMA16(a[i], b[j], acc[i][j]);
    __syncthreads();
  }

  // epilogue: C layout col=lane&15, row=(lane>>4)*4+reg (m89-verified)
#pragma unroll
  for (int j = 0; j < 4; ++j) {
    const int col = n0 + wn + j * 16 + r16;
    const float bv = bias[col];
#pragma unroll
    for (int i = 0; i < 4; ++i) {
#pragma unroll
      for (int rr = 0; rr < 4; ++rr) {
        const int m = m0 + wm + i * 16 + g * 4 + rr;
        const float c = acc[i][j][rr] + bv;
        const int bi = m >> 10, n = m & 1023;
        if (col < 1024) {
          const int z = bi * 16 + (col >> 6), dh = col & 63;
          const size_t idx = ((size_t)z * 1024 + n) * 64 + dh;
          f16 h = (f16)c;
          Qh[idx] = h; Ql[idx] = (f16)(c - (float)h);
        } else if (col < 2048) {
          const int c2 = col - 1024;
          const int z = bi * 16 + (c2 >> 6), dh = c2 & 63;
          const size_t idx = ((size_t)z * 1024 + n) * 64 + dh;
          f16 h = (f16)c;
          Kh[idx] = h; Kl[idx] = (f16)(c - (float)h);
        } else {
          const int c2 = col - 2048;
          const int z = bi * 16 + (c2 >> 6), dh = c2 & 63;
          Vh[((size_t)z * 1024 + n) * 64 + dh] = (f16)c;
        }
      }
    }
  }
}

// --------------------------- V transpose ------------------------------------
// Vh[z][n][dh] -> Vt[z][dh][n]  (so attention PV B-frags read contiguously)
__global__ __launch_bounds__(256) void transp_v(const f16* __restrict__ Vh,
                                                f16* __restrict__ Vt) {
  __shared__ f16 t[64][80];  // pad to 160B rows (16B-aligned, conflict-lite)
  const int z = blockIdx.y, nt = blockIdx.x;
  const int tid = threadIdx.x;
#pragma unroll
  for (int it = 0; it < 2; ++it) {
    int c = tid + it * 256;
    int row = c >> 3, cc = c & 7;
    *(f16x8*)&t[row][cc * 8] =
        *(const f16x8*)&Vh[(((size_t)z << 10) + nt * 64 + row) * 64 + cc * 8];
  }
  __syncthreads();
#pragma unroll
  for (int it = 0; it < 2; ++it) {
    int c = tid + it * 256;
    int dh = c >> 3, ncc = c & 7;
    f16x8 o;
#pragma unroll
    for (int j = 0; j < 8; ++j) o[j] = t[ncc * 8 + j][dh];
    *(f16x8*)&Vt[((size_t)z * 64 + dh) * 1024 + nt * 64 + ncc * 8] = o;
  }
}

// --------------------------- fused attention --------------------------------
// per block: head z, 64 query rows (16 per wave). Online softmax (fp32),
// scores *8 (reference quirk), dropout after softmax (denominator unmasked).
__global__ __launch_bounds__(256) void attn(
    const f16* __restrict__ Qh_, const f16* __restrict__ Ql_,
    const f16* __restrict__ Kh_, const f16* __restrict__ Kl_,
    const f16* __restrict__ Vt_, const float* __restrict__ mask,
    float* __restrict__ out) {
  __shared__ f16 sm[5 * 4096];  // Qh,Ql,Kh,Kl,Vt tiles (64x64 each), 40KB
  f16* Qhs = sm;
  f16* Qls = sm + 4096;
  f16* Khs = sm + 2 * 4096;
  f16* Kls = sm + 3 * 4096;
  f16* Vts = sm + 4 * 4096;
  f16* Ps = Khs;  // P-transpose region aliases Khs (dead after S phase)

  const int z = blockIdx.y, qt = blockIdx.x;
  const int q0 = qt * 64;
  const int tid = threadIdx.x, w = tid >> 6, lane = tid & 63;
  const int r16 = lane & 15, g = lane >> 4;

  // ---- stage Q tiles once (XOR-8 pre-swizzled source, linear LDS dest) ----
  const size_t qbase = ((size_t)z * 1024 + q0) * 64;
#pragma unroll
  for (int it = 0; it < 2; ++it) {
    int c = tid + it * 256;
    int row = c >> 3, p = c & 7, sc = p ^ (row & 7);
    gll16(Qh_ + qbase + row * 64 + sc * 8, &Qhs[c * 8]);
    gll16(Ql_ + qbase + row * 64 + sc * 8, &Qls[c * 8]);
  }
  __syncthreads();

  f16x8 qa[2], qla[2];
#pragma unroll
  for (int ks = 0; ks < 2; ++ks) {
    qa[ks] = ldsfrag(Qhs, w * 16 + r16, ks * 4 + g);
    qla[ks] = ldsfrag(Qls, w * 16 + r16, ks * 4 + g);
  }

  float mrow[4] = {-1e30f, -1e30f, -1e30f, -1e30f};
  float lrow[4] = {0.f, 0.f, 0.f, 0.f};
  f32x4 zero4 = {0.f, 0.f, 0.f, 0.f};
  f32x4 acc[4];
#pragma unroll
  for (int df = 0; df < 4; ++df) acc[df] = zero4;

  const float* mrow_base = mask + ((size_t)z << 20);

  for (int kt = 0; kt < 16; ++kt) {
    const int k0 = kt * 64;
    // ---- stage K (hi+lo) and V^T tiles, swizzled ----
    const size_t kbase = ((size_t)z * 1024 + k0) * 64;
    const size_t vbase = (size_t)z * 64 * 1024 + k0;
#pragma unroll
    for (int it = 0; it < 2; ++it) {
      int c = tid + it * 256;
      int row = c >> 3, p = c & 7, sc = p ^ (row & 7);
      gll16(Kh_ + kbase + row * 64 + sc * 8, &Khs[c * 8]);
      gll16(Kl_ + kbase + row * 64 + sc * 8, &Kls[c * 8]);
      gll16(Vt_ + vbase + (size_t)row * 1024 + sc * 8, &Vts[c * 8]);
    }
    __syncthreads();

    // ---- S = (Q K^T): 3-term hi/lo, C layout col=key(lane&15) ----
    f32x4 s[4];
#pragma unroll
    for (int cf = 0; cf < 4; ++cf) {
      f32x4 t = zero4;
#pragma unroll
      for (int ks = 0; ks < 2; ++ks) {
        f16x8 kh = ldsfrag(Khs, cf * 16 + r16, ks * 4 + g);
        f16x8 kl = ldsfrag(Kls, cf * 16 + r16, ks * 4 + g);
        t = MFMA16(qa[ks], kh, t);
        t = MFMA16(qla[ks], kh, t);
        t = MFMA16(qa[ks], kl, t);
      }
      s[cf] = t;
    }

    // ---- online softmax in fp32 (scores *8 per reference quirk) ----
    float s8[4][4];
#pragma unroll
    for (int cf = 0; cf < 4; ++cf)
#pragma unroll
      for (int rr = 0; rr < 4; ++rr) s8[cf][rr] = s[cf][rr] * 8.0f;

    float rm[4];
#pragma unroll
    for (int rr = 0; rr < 4; ++rr)
      rm[rr] = fmaxf(fmaxf(s8[0][rr], s8[1][rr]), fmaxf(s8[2][rr], s8[3][rr]));
#pragma unroll
    for (int mk = 1; mk < 16; mk <<= 1)
#pragma unroll
      for (int rr = 0; rr < 4; ++rr)
        rm[rr] = fmaxf(rm[rr], __shfl_xor(rm[rr], mk, 64));

    float mnew[4], scal[4];
#pragma unroll
    for (int rr = 0; rr < 4; ++rr) {
      mnew[rr] = fmaxf(mrow[rr], rm[rr]);
      scal[rr] = __expf(mrow[rr] - mnew[rr]);
      mrow[rr] = mnew[rr];
    }

    float p_[4][4], rs[4] = {0.f, 0.f, 0.f, 0.f};
#pragma unroll
    for (int cf = 0; cf < 4; ++cf)
#pragma unroll
      for (int rr = 0; rr < 4; ++rr) {
        p_[cf][rr] = __expf(s8[cf][rr] - mnew[rr]);
        rs[rr] += p_[cf][rr];
      }
#pragma unroll
    for (int mk = 1; mk < 16; mk <<= 1)
#pragma unroll
      for (int rr = 0; rr < 4; ++rr) rs[rr] += __shfl_xor(rs[rr], mk, 64);
#pragma unroll
    for (int rr = 0; rr < 4; ++rr) lrow[rr] = lrow[rr] * scal[rr] + rs[rr];
#pragma unroll
    for (int df = 0; df < 4; ++df)
#pragma unroll
      for (int rr = 0; rr < 4; ++rr) acc[df][rr] *= scal[rr];

    // ---- dropout mask (post-softmax; denominator stays unmasked) ----
    float pm_[4][4];
#pragma unroll
    for (int cf = 0; cf < 4; ++cf)
#pragma unroll
      for (int rr = 0; rr < 4; ++rr) {
        const int qrow = q0 + w * 16 + g * 4 + rr;
        const float mv = mrow_base[(size_t)qrow * 1024 + k0 + cf * 16 + r16];
        pm_[cf][rr] = p_[cf][rr] * mv;
      }

    __syncthreads();  // everyone done reading Khs before P overwrites it

    // ---- write P (f16) into per-wave swizzled LDS region; read A-frags ----
    f16* Pw = Ps + w * 1024;
#pragma unroll
    for (int cf = 0; cf < 4; ++cf)
#pragma unroll
      for (int rr = 0; rr < 4; ++rr) {
        const int prow = g * 4 + rr, key = cf * 16 + r16;
        Pw[prow * 64 + (((key >> 3) ^ (prow & 7)) << 3) + (key & 7)] =
            (f16)pm_[cf][rr];
      }
    // wave-private region: in-order LDS within a wave, compiler inserts waits
    f16x8 pf[2];
#pragma unroll
    for (int ks2 = 0; ks2 < 2; ++ks2) pf[ks2] = ldsfrag(Pw, r16, ks2 * 4 + g);
#pragma unroll
    for (int df = 0; df < 4; ++df)
#pragma unroll
      for (int ks2 = 0; ks2 < 2; ++ks2)
        acc[df] = MFMA16(pf[ks2], ldsfrag(Vts, df * 16 + r16, ks2 * 4 + g),
                         acc[df]);
    __syncthreads();  // P/Vt reads done before next tile staging
  }

  // ---- epilogue: out[b][n][h*64+dh] = acc / l ----
  const int bi = z >> 4, hh = z & 15;
#pragma unroll
  for (int df = 0; df < 4; ++df)
#pragma unroll
    for (int rr = 0; rr < 4; ++rr) {
      const int n = q0 + w * 16 + g * 4 + rr;
      out[((size_t)bi * 1024 + n) * 1024 + hh * 64 + df * 16 + r16] =
          acc[df][rr] / lrow[rr];
    }
}

// --------------------------- launcher ---------------------------------------
extern "C" void kernel_launch(void* const* d_in, const int* in_sizes, int n_in,
                              void* d_out, int out_size, void* d_ws,
                              size_t ws_size, hipStream_t stream) {
  const float* query = (const float*)d_in[0];
  // d_in[1] (key) and d_in[2] (value) are unused by the reference
  const float* W = (const float*)d_in[3];
  const float* bias = (const float*)d_in[4];
  const float* mask = (const float*)d_in[5];
  float* out = (float*)d_out;

  f16* p = (f16*)d_ws;
  f16* qh = p;              p += (size_t)4096 * 1024;
  f16* ql = p;              p += (size_t)4096 * 1024;
  f16* wh = p;              p += (size_t)3072 * 1024;
  f16* wl = p;              p += (size_t)3072 * 1024;
  f16* Qh = p;              p += (size_t)64 * 1024 * 64;
  f16* Ql = p;              p += (size_t)64 * 1024 * 64;
  f16* Kh = p;              p += (size_t)64 * 1024 * 64;
  f16* Kl = p;              p += (size_t)64 * 1024 * 64;
  f16* Vh = p;              p += (size_t)64 * 1024 * 64;
  f16* Vt = p;              // total ~76 MB of workspace

  cvt_split<<<(1048576 + 255) / 256, 256, 0, stream>>>(
      (const float4*)query, (f16x4*)qh, (f16x4*)ql, 1048576);
  cvt_split<<<(786432 + 255) / 256, 256, 0, stream>>>(
      (const float4*)W, (f16x4*)wh, (f16x4*)wl, 786432);
  proj_gemm<<<dim3(24, 32), 256, 0, stream>>>(qh, ql, wh, wl, bias, Qh, Ql, Kh,
                                              Kl, Vh);
  transp_v<<<dim3(16, 64), 256, 0, stream>>>(Vh, Vt);
  attn<<<dim3(16, 64), 256, 0, stream>>>(Qh, Ql, Kh, Kl, Vt, mask, out);
}